// Round 1
// baseline (3156.268 us; speedup 1.0000x reference)
//
#include <hip/hip_runtime.h>

#define N_USER 100000
#define N_ITEM 50000
#define NTOT   150000   // N_USER + N_ITEM
#define D      64
#define NE     2400000
#define LAYERS 3
#define BB     4096

// ---------------------------------------------------------------------------
// init: cur = concat(user_emb, item_emb); sum = cur  (embs[0] term of the mean)
// vectorized float4: NTOT*D/4 = 2.4M float4s
// ---------------------------------------------------------------------------
__global__ __launch_bounds__(256) void init_emb(const float* __restrict__ ue,
                                                const float* __restrict__ ie,
                                                float* __restrict__ cur,
                                                float* __restrict__ sum) {
    int i = blockIdx.x * blockDim.x + threadIdx.x;
    const int total = NTOT * D / 4;
    if (i >= total) return;
    const int userElems = N_USER * D / 4;
    float4 v = (i < userElems) ? ((const float4*)ue)[i]
                               : ((const float4*)ie)[i - userElems];
    ((float4*)cur)[i] = v;
    ((float4*)sum)[i] = v;
}

// ---------------------------------------------------------------------------
// SpMM scatter: out[dst] += val * emb[src], one wave per edge, lane = d.
// 64-lane coalesced 256B gather from emb[src] and coalesced f32 atomics to
// out[dst]. Grid-stride over edges.
// ---------------------------------------------------------------------------
__global__ __launch_bounds__(256) void spmm_atomic(const int*   __restrict__ src,
                                                   const int*   __restrict__ dst,
                                                   const float* __restrict__ val,
                                                   const float* __restrict__ emb,
                                                   float*       __restrict__ out) {
    const int lane = threadIdx.x & 63;
    int wid = blockIdx.x * (blockDim.x >> 6) + (threadIdx.x >> 6);
    const int nw = gridDim.x * (blockDim.x >> 6);
    for (int e = wid; e < NE; e += nw) {
        int   s  = src[e];            // wave-uniform broadcast load
        int   d0 = dst[e];
        float v  = val[e];
        float x  = emb[(size_t)s * D + lane];
        unsafeAtomicAdd(&out[(size_t)d0 * D + lane], v * x);
    }
}

// ---------------------------------------------------------------------------
// combine: per row r:
//   att_side = exp(mean(side*cur + side)); att_sim = exp(mean(sim*cur + sim))
//   cur = (att_side/den)*side + (att_sim/den)*sim;  sum += cur
// one wave per row, lane = d; butterfly reduce over 64 lanes.
// ---------------------------------------------------------------------------
__global__ __launch_bounds__(256) void combine(const float* __restrict__ side,
                                               const float* __restrict__ sim,
                                               float* __restrict__ cur,
                                               float* __restrict__ sum) {
    const int lane = threadIdx.x & 63;
    int row = blockIdx.x * (blockDim.x >> 6) + (threadIdx.x >> 6);
    if (row >= NTOT) return;
    size_t base = (size_t)row * D + lane;
    float c  = cur[base];
    float sd = side[base];
    float sm = sim[base];
    float t1 = sd * c + sd;
    float t2 = sm * c + sm;
    #pragma unroll
    for (int off = 32; off; off >>= 1) {
        t1 += __shfl_xor(t1, off, 64);
        t2 += __shfl_xor(t2, off, 64);
    }
    float a1 = expf(t1 * (1.0f / 64.0f));
    float a2 = expf(t2 * (1.0f / 64.0f));
    float den = a1 + a2;
    float w1 = a1 / den;
    float w2 = a2 / den;
    float nv = w1 * sd + w2 * sm;
    cur[base] = nv;
    sum[base] += nv;
}

// ---------------------------------------------------------------------------
// final: out[b] = dot(0.25*sum[users[b]], 0.25*sum[N_USER+items[b]])
// one wave per b, lane = d.
// ---------------------------------------------------------------------------
__global__ __launch_bounds__(256) void final_dot(const float* __restrict__ sum,
                                                 const int* __restrict__ users,
                                                 const int* __restrict__ items,
                                                 float* __restrict__ out) {
    const int lane = threadIdx.x & 63;
    int b = blockIdx.x * (blockDim.x >> 6) + (threadIdx.x >> 6);
    if (b >= BB) return;
    int u  = users[b];
    int it = items[b];
    float x = sum[(size_t)u * D + lane] * 0.25f;
    float y = sum[(size_t)(N_USER + it) * D + lane] * 0.25f;
    float p = x * y;
    #pragma unroll
    for (int off = 32; off; off >>= 1) p += __shfl_xor(p, off, 64);
    if (lane == 0) out[b] = p;
}

extern "C" void kernel_launch(void* const* d_in, const int* in_sizes, int n_in,
                              void* d_out, int out_size, void* d_ws, size_t ws_size,
                              hipStream_t stream) {
    const float* ue   = (const float*)d_in[0];
    const float* ie   = (const float*)d_in[1];
    const int*   gsrc = (const int*)d_in[2];
    const int*   gdst = (const int*)d_in[3];
    const float* gval = (const float*)d_in[4];
    const int*   ssrc = (const int*)d_in[5];
    const int*   sdst = (const int*)d_in[6];
    const float* sval = (const float*)d_in[7];
    const int*   users = (const int*)d_in[8];
    const int*   items = (const int*)d_in[9];
    float* out = (float*)d_out;

    const size_t rowElems = (size_t)NTOT * D;          // 9.6M floats
    float* cur  = (float*)d_ws;
    float* side = cur  + rowElems;
    float* simb = side + rowElems;
    float* sums = simb + rowElems;
    // total ws use: 4 * 9.6M * 4B = 153.6 MB

    init_emb<<<(NTOT * D / 4 + 255) / 256, 256, 0, stream>>>(ue, ie, cur, sums);

    for (int l = 0; l < LAYERS; ++l) {
        hipMemsetAsync(side, 0, rowElems * sizeof(float), stream);
        hipMemsetAsync(simb, 0, rowElems * sizeof(float), stream);
        spmm_atomic<<<8192, 256, 0, stream>>>(gsrc, gdst, gval, cur, side);
        spmm_atomic<<<8192, 256, 0, stream>>>(ssrc, sdst, sval, cur, simb);
        combine<<<NTOT / 4, 256, 0, stream>>>(side, simb, cur, sums);
    }

    final_dot<<<BB / 4, 256, 0, stream>>>(sums, users, items, out);
}

// Round 2
// 1889.160 us; speedup vs baseline: 1.6707x; 1.6707x over previous
//
#include <hip/hip_runtime.h>

#define N_USER 100000
#define N_ITEM 50000
#define NTOT   150000   // N_USER + N_ITEM
#define D      64
#define NE     2400000
#define LAYERS 3
#define BB     4096

#define SCAN_B 256
#define NBLK   ((NTOT + SCAN_B - 1) / SCAN_B)   // 586 blocks
static_assert(NBLK <= 1024, "scan2 single-block capacity");

// ---------------------------------------------------------------------------
// init: cur = concat(user_emb, item_emb); sum = cur
// ---------------------------------------------------------------------------
__global__ __launch_bounds__(256) void init_emb(const float* __restrict__ ue,
                                                const float* __restrict__ ie,
                                                float* __restrict__ cur,
                                                float* __restrict__ sum) {
    int i = blockIdx.x * blockDim.x + threadIdx.x;
    const int total = NTOT * D / 4;
    if (i >= total) return;
    const int userElems = N_USER * D / 4;
    float4 v = (i < userElems) ? ((const float4*)ue)[i]
                               : ((const float4*)ie)[i - userElems];
    ((float4*)cur)[i] = v;
    ((float4*)sum)[i] = v;
}

// ---------------------------------------------------------------------------
// CSR build: histogram of dst
// ---------------------------------------------------------------------------
__global__ __launch_bounds__(256) void hist_dst(const int* __restrict__ dst,
                                                int* __restrict__ counts) {
    int i = blockIdx.x * blockDim.x + threadIdx.x;
    int stride = gridDim.x * blockDim.x;
    for (; i < NE; i += stride) atomicAdd(&counts[dst[i]], 1);
}

// per-block inclusive scan of counts -> incl, block totals -> bsum
__global__ __launch_bounds__(SCAN_B) void scan_block(const int* __restrict__ counts,
                                                     int* __restrict__ incl,
                                                     int* __restrict__ bsum) {
    __shared__ int s[SCAN_B];
    int tid = threadIdx.x;
    int i = blockIdx.x * SCAN_B + tid;
    s[tid] = (i < NTOT) ? counts[i] : 0;
    __syncthreads();
    #pragma unroll
    for (int off = 1; off < SCAN_B; off <<= 1) {
        int t = (tid >= off) ? s[tid - off] : 0;
        __syncthreads();
        s[tid] += t;
        __syncthreads();
    }
    if (i < NTOT) incl[i] = s[tid];
    if (tid == SCAN_B - 1) bsum[blockIdx.x] = s[tid];
}

// single-block inclusive scan of bsum[NBLK]
__global__ __launch_bounds__(1024) void scan_bsum(int* __restrict__ bsum) {
    __shared__ int s[1024];
    int tid = threadIdx.x;
    s[tid] = (tid < NBLK) ? bsum[tid] : 0;
    __syncthreads();
    #pragma unroll
    for (int off = 1; off < 1024; off <<= 1) {
        int t = (tid >= off) ? s[tid - off] : 0;
        __syncthreads();
        s[tid] += t;
        __syncthreads();
    }
    if (tid < NBLK) bsum[tid] = s[tid];
}

// rowptr[i] = exclusive scan = blockoffset + incl[i] - counts[i]
__global__ __launch_bounds__(SCAN_B) void make_rowptr(const int* __restrict__ incl,
                                                      const int* __restrict__ counts,
                                                      const int* __restrict__ bsum,
                                                      int* __restrict__ rowptr) {
    int i = blockIdx.x * SCAN_B + threadIdx.x;
    if (i < NTOT) {
        int off = blockIdx.x ? bsum[blockIdx.x - 1] : 0;
        rowptr[i] = off + incl[i] - counts[i];
    }
    if (i == 0) rowptr[NTOT] = NE;
}

// scatter edges into CSR slots: srcval[pos] = (src, val)
__global__ __launch_bounds__(256) void scatter_edges(const int*   __restrict__ src,
                                                     const int*   __restrict__ dst,
                                                     const float* __restrict__ val,
                                                     const int*   __restrict__ rowptr,
                                                     int*         __restrict__ fill,
                                                     int2*        __restrict__ srcval) {
    int i = blockIdx.x * blockDim.x + threadIdx.x;
    int stride = gridDim.x * blockDim.x;
    for (; i < NE; i += stride) {
        int d = dst[i];
        int pos = rowptr[d] + atomicAdd(&fill[d], 1);
        srcval[pos] = make_int2(src[i], __float_as_int(val[i]));
    }
}

// ---------------------------------------------------------------------------
// gather-form SpMM: one wave per dst row, lane = d; register accumulate,
// single coalesced 256B store. No atomics.
// ---------------------------------------------------------------------------
__global__ __launch_bounds__(256) void spmm_csr(const int2* __restrict__ srcval,
                                                const int*  __restrict__ rowptr,
                                                const float* __restrict__ emb,
                                                float*       __restrict__ out) {
    const int lane = threadIdx.x & 63;
    int row = blockIdx.x * (blockDim.x >> 6) + (threadIdx.x >> 6);
    if (row >= NTOT) return;
    int p   = rowptr[row];
    int end = rowptr[row + 1];
    float acc = 0.0f;
    for (; p < end; ++p) {
        int2 m = srcval[p];                      // wave-uniform 8B load
        acc = fmaf(__int_as_float(m.y), emb[(size_t)m.x * D + lane], acc);
    }
    out[(size_t)row * D + lane] = acc;
}

// ---------------------------------------------------------------------------
// combine (unchanged): attention mix + running sum
// ---------------------------------------------------------------------------
__global__ __launch_bounds__(256) void combine(const float* __restrict__ side,
                                               const float* __restrict__ sim,
                                               float* __restrict__ cur,
                                               float* __restrict__ sum) {
    const int lane = threadIdx.x & 63;
    int row = blockIdx.x * (blockDim.x >> 6) + (threadIdx.x >> 6);
    if (row >= NTOT) return;
    size_t base = (size_t)row * D + lane;
    float c  = cur[base];
    float sd = side[base];
    float sm = sim[base];
    float t1 = sd * c + sd;
    float t2 = sm * c + sm;
    #pragma unroll
    for (int off = 32; off; off >>= 1) {
        t1 += __shfl_xor(t1, off, 64);
        t2 += __shfl_xor(t2, off, 64);
    }
    float a1 = expf(t1 * (1.0f / 64.0f));
    float a2 = expf(t2 * (1.0f / 64.0f));
    float den = a1 + a2;
    float w1 = a1 / den;
    float w2 = a2 / den;
    float nv = w1 * sd + w2 * sm;
    cur[base] = nv;
    sum[base] += nv;
}

// ---------------------------------------------------------------------------
// final: out[b] = dot(sum[users[b]]/4, sum[N_USER+items[b]]/4)
// ---------------------------------------------------------------------------
__global__ __launch_bounds__(256) void final_dot(const float* __restrict__ sum,
                                                 const int* __restrict__ users,
                                                 const int* __restrict__ items,
                                                 float* __restrict__ out) {
    const int lane = threadIdx.x & 63;
    int b = blockIdx.x * (blockDim.x >> 6) + (threadIdx.x >> 6);
    if (b >= BB) return;
    int u  = users[b];
    int it = items[b];
    float x = sum[(size_t)u * D + lane] * 0.25f;
    float y = sum[(size_t)(N_USER + it) * D + lane] * 0.25f;
    float p = x * y;
    #pragma unroll
    for (int off = 32; off; off >>= 1) p += __shfl_xor(p, off, 64);
    if (lane == 0) out[b] = p;
}

extern "C" void kernel_launch(void* const* d_in, const int* in_sizes, int n_in,
                              void* d_out, int out_size, void* d_ws, size_t ws_size,
                              hipStream_t stream) {
    const float* ue   = (const float*)d_in[0];
    const float* ie   = (const float*)d_in[1];
    const int*   gsrc = (const int*)d_in[2];
    const int*   gdst = (const int*)d_in[3];
    const float* gval = (const float*)d_in[4];
    const int*   ssrc = (const int*)d_in[5];
    const int*   sdst = (const int*)d_in[6];
    const float* sval = (const float*)d_in[7];
    const int*   users = (const int*)d_in[8];
    const int*   items = (const int*)d_in[9];
    float* out = (float*)d_out;

    // ---- workspace carve-up (all 256B-aligned) ----
    char* p = (char*)d_ws;
    auto carve = [&](size_t bytes) { char* r = p; p += (bytes + 255) & ~(size_t)255; return r; };
    const size_t rowElems = (size_t)NTOT * D;                    // 9.6M floats
    float* cur   = (float*)carve(rowElems * 4);
    float* side  = (float*)carve(rowElems * 4);
    float* simb  = (float*)carve(rowElems * 4);
    float* sums  = (float*)carve(rowElems * 4);                  // 153.6 MB
    int2*  svG   = (int2*)carve((size_t)NE * 8);                 // 19.2 MB
    int2*  svS   = (int2*)carve((size_t)NE * 8);                 // 19.2 MB
    int*   rpG   = (int*)carve((size_t)(NTOT + 1) * 4);
    int*   rpS   = (int*)carve((size_t)(NTOT + 1) * 4);
    int*   counts= (int*)carve((size_t)NTOT * 4);
    int*   incl  = (int*)carve((size_t)NTOT * 4);
    int*   fill  = (int*)carve((size_t)NTOT * 4);
    int*   bsum  = (int*)carve(4096);
    (void)ws_size;

    init_emb<<<(NTOT * D / 4 + 255) / 256, 256, 0, stream>>>(ue, ie, cur, sums);

    // ---- CSR build for both edge sets ----
    const int* esrc[2] = {gsrc, ssrc};
    const int* edst[2] = {gdst, sdst};
    const float* eval[2] = {gval, sval};
    int2* sv[2] = {svG, svS};
    int*  rp[2] = {rpG, rpS};
    for (int s = 0; s < 2; ++s) {
        hipMemsetAsync(counts, 0, (size_t)NTOT * 4, stream);
        hipMemsetAsync(fill,   0, (size_t)NTOT * 4, stream);
        hist_dst<<<2048, 256, 0, stream>>>(edst[s], counts);
        scan_block<<<NBLK, SCAN_B, 0, stream>>>(counts, incl, bsum);
        scan_bsum<<<1, 1024, 0, stream>>>(bsum);
        make_rowptr<<<NBLK, SCAN_B, 0, stream>>>(incl, counts, bsum, rp[s]);
        scatter_edges<<<2048, 256, 0, stream>>>(esrc[s], edst[s], eval[s], rp[s], fill, sv[s]);
    }

    // ---- 3 propagation layers ----
    for (int l = 0; l < LAYERS; ++l) {
        spmm_csr<<<(NTOT + 3) / 4, 256, 0, stream>>>(svG, rpG, cur, side);
        spmm_csr<<<(NTOT + 3) / 4, 256, 0, stream>>>(svS, rpS, cur, simb);
        combine<<<(NTOT + 3) / 4, 256, 0, stream>>>(side, simb, cur, sums);
    }

    final_dot<<<BB / 4, 256, 0, stream>>>(sums, users, items, out);
}

// Round 3
// 1078.373 us; speedup vs baseline: 2.9269x; 1.7519x over previous
//
#include <hip/hip_runtime.h>

#define N_USER 100000
#define N_ITEM 50000
#define NTOT   150000   // N_USER + N_ITEM
#define D      64
#define NE     2400000
#define LAYERS 3
#define BB     4096

#define SCAN_B 256
#define NBLK   ((NTOT + SCAN_B - 1) / SCAN_B)   // 586 blocks
static_assert(NBLK <= 1024, "scan2 single-block capacity");

// ---------------------------------------------------------------------------
// init: cur0 = concat(user_emb, item_emb)
// ---------------------------------------------------------------------------
__global__ __launch_bounds__(256) void init_emb(const float* __restrict__ ue,
                                                const float* __restrict__ ie,
                                                float* __restrict__ cur0) {
    int i = blockIdx.x * blockDim.x + threadIdx.x;
    const int total = NTOT * D / 4;
    if (i >= total) return;
    const int userElems = N_USER * D / 4;
    float4 v = (i < userElems) ? ((const float4*)ue)[i]
                               : ((const float4*)ie)[i - userElems];
    ((float4*)cur0)[i] = v;
}

// ---------------------------------------------------------------------------
// CSR build: histogram of dst
// ---------------------------------------------------------------------------
__global__ __launch_bounds__(256) void hist_dst(const int* __restrict__ dst,
                                                int* __restrict__ counts) {
    int i = blockIdx.x * blockDim.x + threadIdx.x;
    int stride = gridDim.x * blockDim.x;
    for (; i < NE; i += stride) atomicAdd(&counts[dst[i]], 1);
}

__global__ __launch_bounds__(SCAN_B) void scan_block(const int* __restrict__ counts,
                                                     int* __restrict__ incl,
                                                     int* __restrict__ bsum) {
    __shared__ int s[SCAN_B];
    int tid = threadIdx.x;
    int i = blockIdx.x * SCAN_B + tid;
    s[tid] = (i < NTOT) ? counts[i] : 0;
    __syncthreads();
    #pragma unroll
    for (int off = 1; off < SCAN_B; off <<= 1) {
        int t = (tid >= off) ? s[tid - off] : 0;
        __syncthreads();
        s[tid] += t;
        __syncthreads();
    }
    if (i < NTOT) incl[i] = s[tid];
    if (tid == SCAN_B - 1) bsum[blockIdx.x] = s[tid];
}

__global__ __launch_bounds__(1024) void scan_bsum(int* __restrict__ bsum) {
    __shared__ int s[1024];
    int tid = threadIdx.x;
    s[tid] = (tid < NBLK) ? bsum[tid] : 0;
    __syncthreads();
    #pragma unroll
    for (int off = 1; off < 1024; off <<= 1) {
        int t = (tid >= off) ? s[tid - off] : 0;
        __syncthreads();
        s[tid] += t;
        __syncthreads();
    }
    if (tid < NBLK) bsum[tid] = s[tid];
}

__global__ __launch_bounds__(SCAN_B) void make_rowptr(const int* __restrict__ incl,
                                                      const int* __restrict__ counts,
                                                      const int* __restrict__ bsum,
                                                      int* __restrict__ rowptr) {
    int i = blockIdx.x * SCAN_B + threadIdx.x;
    if (i < NTOT) {
        int off = blockIdx.x ? bsum[blockIdx.x - 1] : 0;
        rowptr[i] = off + incl[i] - counts[i];
    }
    if (i == 0) rowptr[NTOT] = NE;
}

__global__ __launch_bounds__(256) void scatter_edges(const int*   __restrict__ src,
                                                     const int*   __restrict__ dst,
                                                     const float* __restrict__ val,
                                                     const int*   __restrict__ rowptr,
                                                     int*         __restrict__ fill,
                                                     int2*        __restrict__ srcval) {
    int i = blockIdx.x * blockDim.x + threadIdx.x;
    int stride = gridDim.x * blockDim.x;
    for (; i < NE; i += stride) {
        int d = dst[i];
        int pos = rowptr[d] + atomicAdd(&fill[d], 1);
        srcval[pos] = make_int2(src[i], __float_as_int(val[i]));
    }
}

// ---------------------------------------------------------------------------
// per-row CSR gather with 4-deep MLP unroll
// ---------------------------------------------------------------------------
__device__ __forceinline__ float rowGather(const int2* __restrict__ sv,
                                           int p, int e,
                                           const float* __restrict__ emb,
                                           int lane) {
    float acc = 0.0f;
    for (; p + 4 <= e; p += 4) {
        int2 m0 = sv[p + 0];
        int2 m1 = sv[p + 1];
        int2 m2 = sv[p + 2];
        int2 m3 = sv[p + 3];
        float x0 = emb[(size_t)m0.x * D + lane];
        float x1 = emb[(size_t)m1.x * D + lane];
        float x2 = emb[(size_t)m2.x * D + lane];
        float x3 = emb[(size_t)m3.x * D + lane];
        acc = fmaf(__int_as_float(m0.y), x0, acc);
        acc = fmaf(__int_as_float(m1.y), x1, acc);
        acc = fmaf(__int_as_float(m2.y), x2, acc);
        acc = fmaf(__int_as_float(m3.y), x3, acc);
    }
    for (; p < e; ++p) {
        int2 m = sv[p];
        acc = fmaf(__int_as_float(m.y), emb[(size_t)m.x * D + lane], acc);
    }
    return acc;
}

// ---------------------------------------------------------------------------
// fused layer: side = A_g @ cur ; sim = A_s @ cur ; attention mix -> nxt
// one wave per row, lane = d
// ---------------------------------------------------------------------------
__global__ __launch_bounds__(256) void layer_fused(const int2* __restrict__ svG,
                                                   const int*  __restrict__ rpG,
                                                   const int2* __restrict__ svS,
                                                   const int*  __restrict__ rpS,
                                                   const float* __restrict__ cur,
                                                   float*       __restrict__ nxt) {
    const int lane = threadIdx.x & 63;
    int row = blockIdx.x * (blockDim.x >> 6) + (threadIdx.x >> 6);
    if (row >= NTOT) return;
    size_t base = (size_t)row * D + lane;

    float c    = cur[base];
    float accG = rowGather(svG, rpG[row], rpG[row + 1], cur, lane);
    float accS = rowGather(svS, rpS[row], rpS[row + 1], cur, lane);

    float t1 = accG * c + accG;
    float t2 = accS * c + accS;
    #pragma unroll
    for (int off = 32; off; off >>= 1) {
        t1 += __shfl_xor(t1, off, 64);
        t2 += __shfl_xor(t2, off, 64);
    }
    float a1 = expf(t1 * (1.0f / 64.0f));
    float a2 = expf(t2 * (1.0f / 64.0f));
    float den = a1 + a2;
    float nv = (a1 / den) * accG + (a2 / den) * accS;
    nxt[base] = nv;
}

// ---------------------------------------------------------------------------
// final: mean of 4 layer embeddings at sampled rows, then dot
// ---------------------------------------------------------------------------
__global__ __launch_bounds__(256) void final_dot(const float* __restrict__ c0,
                                                 const float* __restrict__ c1,
                                                 const float* __restrict__ c2,
                                                 const float* __restrict__ c3,
                                                 const int* __restrict__ users,
                                                 const int* __restrict__ items,
                                                 float* __restrict__ out) {
    const int lane = threadIdx.x & 63;
    int b = blockIdx.x * (blockDim.x >> 6) + (threadIdx.x >> 6);
    if (b >= BB) return;
    size_t ub = (size_t)users[b] * D + lane;
    size_t vb = (size_t)(N_USER + items[b]) * D + lane;
    float x = (c0[ub] + c1[ub] + c2[ub] + c3[ub]) * 0.25f;
    float y = (c0[vb] + c1[vb] + c2[vb] + c3[vb]) * 0.25f;
    float p = x * y;
    #pragma unroll
    for (int off = 32; off; off >>= 1) p += __shfl_xor(p, off, 64);
    if (lane == 0) out[b] = p;
}

extern "C" void kernel_launch(void* const* d_in, const int* in_sizes, int n_in,
                              void* d_out, int out_size, void* d_ws, size_t ws_size,
                              hipStream_t stream) {
    const float* ue   = (const float*)d_in[0];
    const float* ie   = (const float*)d_in[1];
    const int*   gsrc = (const int*)d_in[2];
    const int*   gdst = (const int*)d_in[3];
    const float* gval = (const float*)d_in[4];
    const int*   ssrc = (const int*)d_in[5];
    const int*   sdst = (const int*)d_in[6];
    const float* sval = (const float*)d_in[7];
    const int*   users = (const int*)d_in[8];
    const int*   items = (const int*)d_in[9];
    float* out = (float*)d_out;

    // ---- workspace carve-up ----
    char* p = (char*)d_ws;
    auto carve = [&](size_t bytes) { char* r = p; p += (bytes + 255) & ~(size_t)255; return r; };
    const size_t rowElems = (size_t)NTOT * D;                    // 9.6M floats
    float* cur[LAYERS + 1];
    for (int l = 0; l <= LAYERS; ++l) cur[l] = (float*)carve(rowElems * 4);  // 153.6 MB
    int2*  svG   = (int2*)carve((size_t)NE * 8);                 // 19.2 MB
    int2*  svS   = (int2*)carve((size_t)NE * 8);                 // 19.2 MB
    int*   rpG   = (int*)carve((size_t)(NTOT + 1) * 4);
    int*   rpS   = (int*)carve((size_t)(NTOT + 1) * 4);
    int*   counts= (int*)carve((size_t)NTOT * 4);
    int*   incl  = (int*)carve((size_t)NTOT * 4);
    int*   fill  = (int*)carve((size_t)NTOT * 4);
    int*   bsum  = (int*)carve(4096);
    (void)ws_size;

    init_emb<<<(NTOT * D / 4 + 255) / 256, 256, 0, stream>>>(ue, ie, cur[0]);

    // ---- CSR build for both edge sets ----
    const int* esrc[2] = {gsrc, ssrc};
    const int* edst[2] = {gdst, sdst};
    const float* eval[2] = {gval, sval};
    int2* sv[2] = {svG, svS};
    int*  rp[2] = {rpG, rpS};
    for (int s = 0; s < 2; ++s) {
        hipMemsetAsync(counts, 0, (size_t)NTOT * 4, stream);
        hipMemsetAsync(fill,   0, (size_t)NTOT * 4, stream);
        hist_dst<<<2048, 256, 0, stream>>>(edst[s], counts);
        scan_block<<<NBLK, SCAN_B, 0, stream>>>(counts, incl, bsum);
        scan_bsum<<<1, 1024, 0, stream>>>(bsum);
        make_rowptr<<<NBLK, SCAN_B, 0, stream>>>(incl, counts, bsum, rp[s]);
        scatter_edges<<<2048, 256, 0, stream>>>(esrc[s], edst[s], eval[s], rp[s], fill, sv[s]);
    }

    // ---- 3 fused propagation layers (double-buffered) ----
    for (int l = 0; l < LAYERS; ++l) {
        layer_fused<<<(NTOT + 3) / 4, 256, 0, stream>>>(svG, rpG, svS, rpS,
                                                        cur[l], cur[l + 1]);
    }

    final_dot<<<BB / 4, 256, 0, stream>>>(cur[0], cur[1], cur[2], cur[3],
                                          users, items, out);
}